// Round 4
// baseline (33.215 us; speedup 1.0000x reference)
//
#include <hip/hip_runtime.h>

// EmbeddingBag(mode='mean'): B=1024, S=256, W=16, EMB=50, vocab=256.
// Round 4: bf16 table in LDS, 8 lanes/bag.
//  - Table stored as bf16 (RNE), row stride 72 bf16 = 144 B. Read window per
//    bag = 128 B = 32 consecutive dwords -> each bank hit exactly once per
//    bag -> a wave's ds_read_b128 (8 bags) is perfectly bank-uniform (8/bank).
//  - 8 lanes/bag (tid&7): no integer division, zero idle lanes.
//  - 64 bags/chunk * 4096 chunks = 1024 blocks * exactly 4 iters: no tail.
//  - 37 KB LDS, 512-thread blocks, 4 blocks/CU = 32 waves (full occupancy).
//  - Early exit on groups of 4 chars; sentinel zero row 256 masks partials.
//  - Accuracy: bf16 RNE entry error <= ~0.009 abs; mean doesn't amplify;
//    harness threshold 8.125e-2 -> ~8x margin.

constexpr int W        = 16;
constexpr int EMB      = 50;
constexpr int RSTRIDE  = 72;                 // bf16 elems per row (144 B)
constexpr int ROWS     = 257;                // 256 vocab + zero sentinel
constexpr int TBL_E    = ROWS * RSTRIDE;     // 18504 bf16
constexpr int TBL_DW   = TBL_E / 2;          // 9252 dwords
constexpr int LUT0_DW  = TBL_DW;             // 1/len LUT (fp32), 17 entries
constexpr int NBAGS    = 1024 * 256;         // 262144
constexpr int BLOCK    = 512;
constexpr int BAGS_PER_CHUNK = BLOCK / 8;    // 64
constexpr int NCHUNK   = NBAGS / BAGS_PER_CHUNK;  // 4096
constexpr int BLOCKS   = 1024;               // 4 chunks per block, exact

__device__ __forceinline__ unsigned bf16_rne(float f) {
    unsigned u = __float_as_uint(f);
    u += 0x7fffu + ((u >> 16) & 1u);         // round-to-nearest-even
    return u >> 16;
}

__global__ __launch_bounds__(BLOCK, 8) void embag_bf16_kernel(
    const int*   __restrict__ chars,     // [NBAGS, W]
    const int*   __restrict__ lengths,   // [NBAGS]
    const float* __restrict__ table,     // [256, EMB]
    float*       __restrict__ out)       // [NBAGS, EMB]
{
    __shared__ unsigned lds_u[TBL_DW + 17];

    // Stage table as packed bf16 pairs. Pair (2i, 2i+1) never straddles a row
    // (RSTRIDE even). Row 256 and cols 50..71 are zeros.
    for (int i = threadIdx.x; i < TBL_DW; i += BLOCK) {
        const int r = i / 36;                // row of elems 2i, 2i+1
        const int c = 2 * i - r * RSTRIDE;   // even, 0..70
        const float f0 = (r < 256 && c     < EMB) ? table[r * EMB + c]     : 0.f;
        const float f1 = (r < 256 && c + 1 < EMB) ? table[r * EMB + c + 1] : 0.f;
        lds_u[i] = bf16_rne(f0) | (bf16_rne(f1) << 16);
    }
    if (threadIdx.x < 17) {
        const float inv = threadIdx.x ? 1.f / (float)threadIdx.x : 0.f;
        lds_u[LUT0_DW + threadIdx.x] = __float_as_uint(inv);
    }
    __syncthreads();

    const int lb = threadIdx.x >> 3;         // bag within chunk, 0..63
    const int t  = threadIdx.x & 7;          // 16B slot within row
    const unsigned lanebyte = (unsigned)t * 16u;
    const char* ldsb = reinterpret_cast<const char*>(lds_u);

    for (int chunk = blockIdx.x; chunk < NCHUNK; chunk += BLOCKS) {
        const int bag = chunk * BAGS_PER_CHUNK + lb;
        const int len = lengths[bag];

        const int4* cp = reinterpret_cast<const int4*>(chars + (size_t)bag * W);
        const int4 c0 = cp[0], c1 = cp[1], c2 = cp[2], c3 = cp[3];

        float a0 = 0.f, a1 = 0.f, a2 = 0.f, a3 = 0.f;
        float a4 = 0.f, a5 = 0.f, a6 = 0.f, a7 = 0.f;

        // One row gather: ds_read_b128 of this lane's 8 bf16, unpack+add.
        #define DO_ROW(eidx, wpos)                                            \
            {                                                                 \
                const int e = ((wpos) < len) ? (eidx) : 256;                  \
                const uint4 v = *reinterpret_cast<const uint4*>(              \
                    ldsb + (unsigned)e * 144u + lanebyte);                    \
                a0 += __uint_as_float(v.x << 16);                             \
                a1 += __uint_as_float(v.x & 0xffff0000u);                     \
                a2 += __uint_as_float(v.y << 16);                             \
                a3 += __uint_as_float(v.y & 0xffff0000u);                     \
                a4 += __uint_as_float(v.z << 16);                             \
                a5 += __uint_as_float(v.z & 0xffff0000u);                     \
                a6 += __uint_as_float(v.w << 16);                             \
                a7 += __uint_as_float(v.w & 0xffff0000u);                     \
            }

        DO_ROW(c0.x, 0) DO_ROW(c0.y, 1) DO_ROW(c0.z, 2) DO_ROW(c0.w, 3)
        if (len > 4) {
            DO_ROW(c1.x, 4) DO_ROW(c1.y, 5) DO_ROW(c1.z, 6) DO_ROW(c1.w, 7)
            if (len > 8) {
                DO_ROW(c2.x, 8) DO_ROW(c2.y, 9) DO_ROW(c2.z, 10) DO_ROW(c2.w, 11)
                if (len > 12) {
                    DO_ROW(c3.x, 12) DO_ROW(c3.y, 13) DO_ROW(c3.z, 14) DO_ROW(c3.w, 15)
                }
            }
        }
        #undef DO_ROW

        const float inv = __uint_as_float(lds_u[LUT0_DW + len]);

        // Lane t owns output elems 8t..8t+7; valid up to 50 (t=6: two, t=7: none).
        float* ob = out + (size_t)bag * EMB + (unsigned)t * 8u;
        if (t < 6) {
            reinterpret_cast<float2*>(ob)[0] = make_float2(a0 * inv, a1 * inv);
            reinterpret_cast<float2*>(ob)[1] = make_float2(a2 * inv, a3 * inv);
            reinterpret_cast<float2*>(ob)[2] = make_float2(a4 * inv, a5 * inv);
            reinterpret_cast<float2*>(ob)[3] = make_float2(a6 * inv, a7 * inv);
        } else if (t == 6) {
            reinterpret_cast<float2*>(ob)[0] = make_float2(a0 * inv, a1 * inv);
        }
    }
}

extern "C" void kernel_launch(void* const* d_in, const int* in_sizes, int n_in,
                              void* d_out, int out_size, void* d_ws, size_t ws_size,
                              hipStream_t stream) {
    const int*   chars   = (const int*)d_in[0];   // [B,S,W] int32
    const int*   lengths = (const int*)d_in[1];   // [B,S]   int32
    const float* table   = (const float*)d_in[2]; // [256,50] f32
    float*       out     = (float*)d_out;         // [B,S,50] f32

    embag_bf16_kernel<<<dim3(BLOCKS), dim3(BLOCK), 0, stream>>>(
        chars, lengths, table, out);
}

// Round 5
// 29.708 us; speedup vs baseline: 1.1181x; 1.1181x over previous
//
#include <hip/hip_runtime.h>

// EmbeddingBag(mean): B=1024, S=256, W=16, EMB=50, vocab=256.
// Round 5: fp32 LDS table (r3 structure, known-good) + per-block length sort.
//  - Each block owns 512 contiguous bags (512 blocks x 512 = 262144, exact).
//  - Sort bag ids by len (17-bin LDS histogram + atomic ticket + prefix);
//    process in sorted order -> waves are length-uniform -> DS rows per wave
//    drops from ~15.5 (wave-max of uniform[1,16]) to ~8.7 (~E[len]).
//  - Per-row nested if(len>k): execz skips rows past the wave's max len.
//    No sentinel row, no cndmask.
//  - 13 lanes/bag, ds_read_b128, row stride 56 dwords (224 B).
//  - 1024-thr blocks, 58.5 KB LDS -> 2 blocks/CU, LB(1024,8) -> VGPR<=64
//    (r3 measured 40 with same inner loop).

constexpr int EMB     = 50;
constexpr int RSTRIDE = 56;                  // dwords per padded row
constexpr int TBL_F   = 256 * RSTRIDE;       // 14336 floats = 57344 B
constexpr int NBAGS   = 1024 * 256;          // 262144
constexpr int BLOCK   = 1024;
constexpr int TPB     = 13;                  // lanes per bag
constexpr int BPP     = BLOCK / TPB;         // 78 bags per pass
constexpr int CHUNK   = 512;                 // bags per block
constexpr int NPASS   = (CHUNK + BPP - 1) / BPP;  // 7 (last pass 44 bags)
constexpr int BLOCKS  = NBAGS / CHUNK;       // 512, exact

__global__ __launch_bounds__(BLOCK, 8) void embag_sorted_kernel(
    const int*   __restrict__ chars,     // [NBAGS, W=16]
    const int*   __restrict__ lengths,   // [NBAGS]
    const float* __restrict__ table,     // [256, EMB]
    float*       __restrict__ out)       // [NBAGS, EMB]
{
    __shared__ float    tbl[TBL_F];
    __shared__ unsigned short order[CHUNK];   // (len<<9) | local_bag_id
    __shared__ unsigned bins[17];
    __shared__ float    invl[17];

    // Stage table into padded fp32 layout (cols 50..55 zero).
    for (int i = threadIdx.x; i < TBL_F; i += BLOCK) {
        const int r = i / RSTRIDE;
        const int c = i - r * RSTRIDE;
        tbl[i] = (c < EMB) ? table[r * EMB + c] : 0.0f;
    }
    if (threadIdx.x < 17) {
        bins[threadIdx.x] = 0;
        invl[threadIdx.x] = threadIdx.x ? 1.0f / (float)threadIdx.x : 0.0f;
    }
    __syncthreads();

    const int base = blockIdx.x * CHUNK;

    // Histogram lens with per-thread ticket.
    int myLen = 0, myTicket = 0;
    if (threadIdx.x < CHUNK) {
        myLen = lengths[base + threadIdx.x];          // in [1,16]
        myTicket = atomicAdd(&bins[myLen], 1u);
    }
    __syncthreads();
    if (threadIdx.x == 0) {                            // exclusive prefix, 16 bins
        unsigned s = 0;
        for (int l = 1; l <= 16; ++l) { unsigned c = bins[l]; bins[l] = s; s += c; }
    }
    __syncthreads();
    if (threadIdx.x < CHUNK)
        order[bins[myLen] + myTicket] =
            (unsigned short)((myLen << 9) | threadIdx.x);
    __syncthreads();

    const int  lb     = threadIdx.x / TPB;             // bag slot in pass
    const int  t      = threadIdx.x - lb * TPB;        // 16B slot in row
    const bool active = (lb < BPP);
    const float* rowp = tbl + 4 * t;

    for (int p = 0; p < NPASS; ++p) {
        const int oi = p * BPP + lb;
        if (!active || oi >= CHUNK) continue;

        const unsigned o   = order[oi];
        const int      len = (int)(o >> 9);
        const int      bag = base + (int)(o & 511u);

        const int4* cp = reinterpret_cast<const int4*>(chars + (size_t)bag * 16);
        const int4 c0 = cp[0], c1 = cp[1], c2 = cp[2], c3 = cp[3];

        float4 acc = make_float4(0.f, 0.f, 0.f, 0.f);

        #define G(comp)                                                        \
            {                                                                  \
                const float4 v =                                               \
                    *reinterpret_cast<const float4*>(rowp + (comp) * RSTRIDE); \
                acc.x += v.x; acc.y += v.y; acc.z += v.z; acc.w += v.w;        \
            }

        // Sorted order -> waves mostly length-uniform -> execz exits exactly
        // at the wave's len; rows issued per wave ~ E[len] = 8.5.
        G(c0.x)
        if (len > 1)  { G(c0.y)
        if (len > 2)  { G(c0.z)
        if (len > 3)  { G(c0.w)
        if (len > 4)  { G(c1.x)
        if (len > 5)  { G(c1.y)
        if (len > 6)  { G(c1.z)
        if (len > 7)  { G(c1.w)
        if (len > 8)  { G(c2.x)
        if (len > 9)  { G(c2.y)
        if (len > 10) { G(c2.z)
        if (len > 11) { G(c2.w)
        if (len > 12) { G(c3.x)
        if (len > 13) { G(c3.y)
        if (len > 14) { G(c3.z)
        if (len > 15) { G(c3.w) }}}}}}}}}}}}}}}
        #undef G

        const float inv = invl[len];
        float* ob = out + (size_t)bag * EMB + 4u * (unsigned)t;
        reinterpret_cast<float2*>(ob)[0] = make_float2(acc.x * inv, acc.y * inv);
        if (t < 12)
            reinterpret_cast<float2*>(ob)[1] = make_float2(acc.z * inv, acc.w * inv);
    }
}

extern "C" void kernel_launch(void* const* d_in, const int* in_sizes, int n_in,
                              void* d_out, int out_size, void* d_ws, size_t ws_size,
                              hipStream_t stream) {
    const int*   chars   = (const int*)d_in[0];   // [B,S,W] int32
    const int*   lengths = (const int*)d_in[1];   // [B,S]   int32
    const float* table   = (const float*)d_in[2]; // [256,50] f32
    float*       out     = (float*)d_out;         // [B,S,50] f32

    embag_sorted_kernel<<<dim3(BLOCKS), dim3(BLOCK), 0, stream>>>(
        chars, lengths, table, out);
}

// Round 6
// 24.877 us; speedup vs baseline: 1.3352x; 1.1942x over previous
//
#include <hip/hip_runtime.h>

// EmbeddingBag(mean): B=1024, S=256, W=16, EMB=50, vocab=256.
// Round 6: r3 gather structure + global-latency hiding.
//  - Theory: r3/r5 stall on two serialized dependent global loads per pass
//    (len -> branch tree, chars int4 -> gather addresses); VALUBusy 13.5%
//    and ~50% no-issue cycles in r5's profile. Fix latency, keep gathers.
//  - lengths: staged once per block into LDS (coalesced int4).
//  - chars: software-pipelined -- pass p issues pass p+1's 4x int4 loads
//    before gathering pass p, so HBM latency hides under ~16 ds_read_b128.
//  - Each block owns 512 contiguous bags: 512 blocks x 7 passes x 78 bags.
//    Coalesced stores (no sort, no scatter, no main-loop barriers).
//  - 13 lanes/bag, ds_read_b128, fp32 rows padded to 56 dwords.

constexpr int EMB     = 50;
constexpr int RSTRIDE = 56;                  // dwords per padded row
constexpr int TBL_F   = 256 * RSTRIDE;       // 14336 floats = 57344 B
constexpr int NBAGS   = 1024 * 256;          // 262144
constexpr int BLOCK   = 1024;
constexpr int TPB     = 13;                  // lanes per bag
constexpr int BPP     = BLOCK / TPB;         // 78 bags per pass
constexpr int CHUNK   = 512;                 // bags per block
constexpr int NPASS   = (CHUNK + BPP - 1) / BPP;  // 7 (last pass 44 bags)
constexpr int BLOCKS  = NBAGS / CHUNK;       // 512, exact

__global__ __launch_bounds__(BLOCK, 8) void embag_pipe_kernel(
    const int*   __restrict__ chars,     // [NBAGS, W=16]
    const int*   __restrict__ lengths,   // [NBAGS]
    const float* __restrict__ table,     // [256, EMB]
    float*       __restrict__ out)       // [NBAGS, EMB]
{
    __shared__ float tbl[TBL_F];
    __shared__ int   lenbuf[CHUNK];
    __shared__ float invl[17];

    const int base = blockIdx.x * CHUNK;

    // Stage table into padded fp32 layout (cols 50..55 zero).
    for (int i = threadIdx.x; i < TBL_F; i += BLOCK) {
        const int r = i / RSTRIDE;
        const int c = i - r * RSTRIDE;
        tbl[i] = (c < EMB) ? table[r * EMB + c] : 0.0f;
    }
    // Stage this block's 512 lengths (coalesced int4 x 128).
    if (threadIdx.x < CHUNK / 4)
        reinterpret_cast<int4*>(lenbuf)[threadIdx.x] =
            reinterpret_cast<const int4*>(lengths + base)[threadIdx.x];
    if (threadIdx.x < 17)
        invl[threadIdx.x] = threadIdx.x ? 1.0f / (float)threadIdx.x : 0.0f;
    __syncthreads();

    const int  lb     = threadIdx.x / TPB;             // bag slot in pass
    const int  t      = threadIdx.x - lb * TPB;        // 16B slot in row
    const bool active = (lb < BPP);
    const float* rowp = tbl + 4 * t;

    // Prologue: prefetch pass-0 chars (clamped address; lb>=78 lanes load
    // bag 0 harmlessly).
    int idx = active ? lb : 0;                          // bag index in chunk
    const int4* cp = reinterpret_cast<const int4*>(chars + (size_t)(base + idx) * 16);
    int4 c0 = cp[0], c1 = cp[1], c2 = cp[2], c3 = cp[3];

    for (int p = 0; p < NPASS; ++p) {
        // Issue next pass's chars loads NOW; they retire during the gathers.
        const int idxn = (idx + BPP < CHUNK) ? idx + BPP : CHUNK - 1;
        const int4* cpn =
            reinterpret_cast<const int4*>(chars + (size_t)(base + idxn) * 16);
        const int4 n0 = cpn[0], n1 = cpn[1], n2 = cpn[2], n3 = cpn[3];

        if (active && idx < CHUNK) {
            const int len = lenbuf[idx];                // LDS, ~free

            float4 acc = make_float4(0.f, 0.f, 0.f, 0.f);

            #define G(comp)                                                        \
                {                                                                  \
                    const float4 v =                                               \
                        *reinterpret_cast<const float4*>(rowp + (comp) * RSTRIDE); \
                    acc.x += v.x; acc.y += v.y; acc.z += v.z; acc.w += v.w;        \
                }
            G(c0.x)
            if (len > 1)  { G(c0.y)
            if (len > 2)  { G(c0.z)
            if (len > 3)  { G(c0.w)
            if (len > 4)  { G(c1.x)
            if (len > 5)  { G(c1.y)
            if (len > 6)  { G(c1.z)
            if (len > 7)  { G(c1.w)
            if (len > 8)  { G(c2.x)
            if (len > 9)  { G(c2.y)
            if (len > 10) { G(c2.z)
            if (len > 11) { G(c2.w)
            if (len > 12) { G(c3.x)
            if (len > 13) { G(c3.y)
            if (len > 14) { G(c3.z)
            if (len > 15) { G(c3.w) }}}}}}}}}}}}}}}
            #undef G

            const float inv = invl[len];
            float* ob = out + (size_t)(base + idx) * EMB + 4u * (unsigned)t;
            reinterpret_cast<float2*>(ob)[0] = make_float2(acc.x * inv, acc.y * inv);
            if (t < 12)
                reinterpret_cast<float2*>(ob)[1] = make_float2(acc.z * inv, acc.w * inv);
        }

        c0 = n0; c1 = n1; c2 = n2; c3 = n3;
        idx += BPP;
    }
}

extern "C" void kernel_launch(void* const* d_in, const int* in_sizes, int n_in,
                              void* d_out, int out_size, void* d_ws, size_t ws_size,
                              hipStream_t stream) {
    const int*   chars   = (const int*)d_in[0];   // [B,S,W] int32
    const int*   lengths = (const int*)d_in[1];   // [B,S]   int32
    const float* table   = (const float*)d_in[2]; // [256,50] f32
    float*       out     = (float*)d_out;         // [B,S,50] f32

    embag_pipe_kernel<<<dim3(BLOCKS), dim3(BLOCK), 0, stream>>>(
        chars, lengths, table, out);
}